// Round 1
// 261.543 us; speedup vs baseline: 1.0102x; 1.0102x over previous
//
#include <hip/hip_runtime.h>
#include <math.h>

// B=32, C=3, H=W=512, window 11, sigma 1.5, VALID conv -> 502x502
#define H 512
#define W 512
#define OUT_H 502
#define OUT_W 502
#define C1c 1.0e-4f   // (0.01*1)^2
#define C2c 9.0e-4f   // (0.03*1)^2

#define TH 56             // output rows per block
#define NR (TH + 10)      // 66 input rows processed (66 = 6*11, phase-aligned)
#define RING_N 528        // 512 cols + 16 pad (threads near right edge read to col 521)

// Row-streaming SSIM, 2 output columns per thread:
//  - one 256-thread block covers the FULL 512-col width (no column halo, no grid.x)
//  - each thread owns cols (2t, 2t+1); the 12-element input strip starting at the
//    even col 2t is read as six aligned ds_read_b128; the x1^2/x2^2/x1*x2 products
//    are computed ONCE per element and shared by both columns' horizontal FMAs.
//  - Gaussian weights live in SGPRs (readfirstlane) -> vertical scatter is pure
//    v_fmac_f32 acc, s, v.
//  - last row-block is shifted up so no per-row address clamping is needed;
//    row ownership (oy >= oyb) removes the duplicated rows from the sum.
__global__ __launch_bounds__(256, 2)
void ssim_kernel(const float* __restrict__ img1,
                 const float* __restrict__ img2,
                 float* __restrict__ out) {
    __shared__ float2 ring[2][RING_N];   // (img1, img2) interleaved pairs
    __shared__ float wsum[4];

    const int tid = threadIdx.x;

    // Gaussian weights (runtime expf to match reference bit-for-bit), -> SGPR
    float g[11];
    {
        float s = 0.f;
#pragma unroll
        for (int i = 0; i < 11; ++i) {
            float d = (float)(i - 5);
            g[i] = expf(-d * d * (1.0f / 4.5f));
            s += g[i];
        }
        float inv = 1.0f / s;
#pragma unroll
        for (int i = 0; i < 11; ++i) {
            g[i] *= inv;
            g[i] = __uint_as_float(__builtin_amdgcn_readfirstlane(__float_as_uint(g[i])));
        }
    }

    const int oyb = blockIdx.x * TH;      // output rows owned: [oyb, oyb+TH)
    const int Y0  = min(oyb, H - NR);     // shift last block up; all rows in-bounds
    const int plane = blockIdx.y;         // b*3 + c
    const size_t pbase = (size_t)plane * (H * W);
    const float* __restrict__ p1 = img1 + pbase;
    const float* __restrict__ p2 = img2 + pbase;

    const int c0 = 2 * tid;               // this thread's even column
    const bool v0ok = (c0 < OUT_W);
    const bool v1ok = (c0 + 1 < OUT_W);

    // zero the pad region once (cols 512..527 of both slots) so edge reads are benign
    if (tid < RING_N - W) {
        ring[0][W + tid] = make_float2(0.f, 0.f);
        ring[1][W + tid] = make_float2(0.f, 0.f);
    }

    // 11 phase slots of vertical partial sums, 5 quantities x 2 columns
    float a0A[11], a1A[11], a2A[11], a3A[11], a4A[11];
    float a0B[11], a1B[11], a2B[11], a3B[11], a4B[11];
#pragma unroll
    for (int i = 0; i < 11; ++i) {
        a0A[i]=0.f; a1A[i]=0.f; a2A[i]=0.f; a3A[i]=0.f; a4A[i]=0.f;
        a0B[i]=0.f; a1B[i]=0.f; a2B[i]=0.f; a3B[i]=0.f; a4B[i]=0.f;
    }

    float lsum = 0.f;

    // 1-row register prefetch; simple strided advance with a cap (no per-row min on y)
    int fidx = Y0 * W + c0;
    const int fcap = (H - 1) * W + c0;
    float2 va = *(const float2*)(p1 + fidx);
    float2 vb = *(const float2*)(p2 + fidx);

#pragma unroll 1
    for (int rb = 0; rb < NR; rb += 11) {
#pragma unroll
        for (int p = 0; p < 11; ++p) {
            const int r = rb + p;
            const int slot = r & 1;

            // stage current row: one ds_write_b128 (cols 2t,2t+1 interleaved pairs)
            *(float4*)&ring[slot][c0] = make_float4(va.x, vb.x, va.y, vb.y);

            // prefetch next row into registers
            fidx = min(fidx + W, fcap);
            va = *(const float2*)(p1 + fidx);
            vb = *(const float2*)(p2 + fidx);

            __syncthreads();

            // horizontal conv for both columns; products computed once per element
            float hA0=0.f,hA1=0.f,hA2=0.f,hA3=0.f,hA4=0.f;
            float hB0=0.f,hB1=0.f,hB2=0.f,hB3=0.f,hB4=0.f;
            const float4* rp = (const float4*)&ring[slot][c0];
#pragma unroll
            for (int k = 0; k < 6; ++k) {
                const float4 f = rp[k];            // elements 2k (x,y) and 2k+1 (z,w)
                {   // element e = 2k
                    const int e = 2 * k;
                    const float x = f.x, y = f.y;
                    const float q2 = x * x, q3 = y * y, q4 = x * y;
                    if (e <= 10) {
                        const float w = g[e];
                        hA0 = fmaf(w, x,  hA0); hA1 = fmaf(w, y,  hA1);
                        hA2 = fmaf(w, q2, hA2); hA3 = fmaf(w, q3, hA3);
                        hA4 = fmaf(w, q4, hA4);
                    }
                    if (e >= 1) {
                        const float w = g[e - 1];
                        hB0 = fmaf(w, x,  hB0); hB1 = fmaf(w, y,  hB1);
                        hB2 = fmaf(w, q2, hB2); hB3 = fmaf(w, q3, hB3);
                        hB4 = fmaf(w, q4, hB4);
                    }
                }
                {   // element e = 2k+1
                    const int e = 2 * k + 1;
                    const float x = f.z, y = f.w;
                    const float q2 = x * x, q3 = y * y, q4 = x * y;
                    if (e <= 10) {
                        const float w = g[e];
                        hA0 = fmaf(w, x,  hA0); hA1 = fmaf(w, y,  hA1);
                        hA2 = fmaf(w, q2, hA2); hA3 = fmaf(w, q3, hA3);
                        hA4 = fmaf(w, q4, hA4);
                    }
                    {   // e >= 1 always true here
                        const float w = g[e - 1];
                        hB0 = fmaf(w, x,  hB0); hB1 = fmaf(w, y,  hB1);
                        hB2 = fmaf(w, q2, hB2); hB3 = fmaf(w, q3, hB3);
                        hB4 = fmaf(w, q4, hB4);
                    }
                }
            }

            // vertical scatter: row r contributes weight g[(p-a) mod 11] to slot a
#pragma unroll
            for (int a = 0; a < 11; ++a) {
                const float w = g[(p - a + 11) % 11];   // compile-time index -> SGPR
                a0A[a] = fmaf(w, hA0, a0A[a]); a1A[a] = fmaf(w, hA1, a1A[a]);
                a2A[a] = fmaf(w, hA2, a2A[a]); a3A[a] = fmaf(w, hA3, a3A[a]);
                a4A[a] = fmaf(w, hA4, a4A[a]);
                a0B[a] = fmaf(w, hB0, a0B[a]); a1B[a] = fmaf(w, hB1, a1B[a]);
                a2B[a] = fmaf(w, hB2, a2B[a]); a3B[a] = fmaf(w, hB3, a3B[a]);
                a4B[a] = fmaf(w, hB4, a4B[a]);
            }

            // output row oy = Y0 + r - 10 completes in slot e = (p+1)%11
            const int e = (p + 1) % 11;
            if (r >= 10) {
                const int oy = Y0 + r - 10;
                if (oy >= oyb) {                  // row ownership (de-dup last block)
                    {   // column A (c0)
                        const float m1 = a0A[e], m2 = a1A[e];
                        const float m1s = m1 * m1, m2s = m2 * m2, m12 = m1 * m2;
                        const float sig1  = a2A[e] - m1s;
                        const float sig2  = a3A[e] - m2s;
                        const float sig12 = a4A[e] - m12;
                        const float num = (2.f * m12 + C1c) * (2.f * sig12 + C2c);
                        const float den = (m1s + m2s + C1c) * (sig1 + sig2 + C2c);
                        const float v = num * __builtin_amdgcn_rcpf(den);
                        if (v0ok) lsum += v;
                    }
                    {   // column B (c0+1)
                        const float m1 = a0B[e], m2 = a1B[e];
                        const float m1s = m1 * m1, m2s = m2 * m2, m12 = m1 * m2;
                        const float sig1  = a2B[e] - m1s;
                        const float sig2  = a3B[e] - m2s;
                        const float sig12 = a4B[e] - m12;
                        const float num = (2.f * m12 + C1c) * (2.f * sig12 + C2c);
                        const float den = (m1s + m2s + C1c) * (sig1 + sig2 + C2c);
                        const float v = num * __builtin_amdgcn_rcpf(den);
                        if (v1ok) lsum += v;
                    }
                }
            }
            a0A[e]=0.f; a1A[e]=0.f; a2A[e]=0.f; a3A[e]=0.f; a4A[e]=0.f;
            a0B[e]=0.f; a1B[e]=0.f; a2B[e]=0.f; a3B[e]=0.f; a4B[e]=0.f;
        }
    }

    // block reduce + one atomic per block
#pragma unroll
    for (int off = 32; off > 0; off >>= 1) lsum += __shfl_down(lsum, off, 64);
    if ((tid & 63) == 0) wsum[tid >> 6] = lsum;
    __syncthreads();
    if (tid == 0) {
        const float inv_count = 1.0f / (3.0f * (float)OUT_H * (float)OUT_W);
        const float total = (wsum[0] + wsum[1] + wsum[2] + wsum[3]) * inv_count;
        atomicAdd(&out[plane / 3], total);
    }
}

__global__ void zero_out(float* out, int n) {
    int i = threadIdx.x + blockIdx.x * blockDim.x;
    if (i < n) out[i] = 0.f;
}

extern "C" void kernel_launch(void* const* d_in, const int* in_sizes, int n_in,
                              void* d_out, int out_size, void* d_ws, size_t ws_size,
                              hipStream_t stream) {
    const float* img1 = (const float*)d_in[0];
    const float* img2 = (const float*)d_in[1];
    float* out = (float*)d_out;

    zero_out<<<1, 64, 0, stream>>>(out, out_size);

    const int nplanes = in_sizes[0] / (H * W);          // 96
    dim3 grid((OUT_H + TH - 1) / TH,                    // 9 row-tiles
              nplanes);                                 // 96 planes
    ssim_kernel<<<grid, 256, 0, stream>>>(img1, img2, out);
}